// Round 10
// baseline (371.519 us; speedup 1.0000x reference)
//
#include <hip/hip_runtime.h>
#include <hip/hip_bf16.h>

#define M_NODES 100000
#define E_EDGES 3200000
#define NBUCK 196          // ceil(100000 / 512)
#define BSHIFT 9           // bucket = row >> 9 (512 rows per bucket)
#define BCAP 24576         // fixed bucket capacity (avg 16327, sd ~127)
#define K3_EPB 8192        // edges per partition block
#define K3_BLOCKS 391      // ceil(E_EDGES / K3_EPB)
#define TILESM 391         // ceil(100000 / 256)
#define GEMM1_BLOCKS 784   // 8 XCD * 49 * 2

typedef __attribute__((ext_vector_type(8))) short short8;
typedef __attribute__((ext_vector_type(4))) float f32x4;
typedef __attribute__((ext_vector_type(2))) float f32x2;

__device__ inline unsigned short f2bf(float f) {
  __hip_bfloat16 h = __float2bfloat16(f);
  return __builtin_bit_cast(unsigned short, h);
}

// ---------------- fp8 e4m3 helpers (HW path on gfx950) ----------------
#if __has_builtin(__builtin_amdgcn_cvt_pk_f32_fp8) && __has_builtin(__builtin_amdgcn_cvt_pk_fp8_f32)
#define HW_FP8 1
#endif

#ifndef HW_FP8
__device__ inline float fp8_dec1(unsigned int b) {
  const unsigned int s = (b >> 7) & 1u, e = (b >> 3) & 15u, m = b & 7u;
  float v;
  if (e == 0) v = (float)m * 0.001953125f;  // 2^-9
  else v = __uint_as_float(((e + 120u) << 23) | (m << 20));
  return s ? -v : v;
}
__device__ inline unsigned int fp8_enc1(float x) {
  const unsigned int sb = (__float_as_uint(x) >> 31) << 7;
  float ax = fminf(fabsf(x), 448.f);
  if (ax < 0.0009765625f) return sb;
  const unsigned int xb = __float_as_uint(ax);
  const int ef = (int)(xb >> 23) - 127;
  if (ef < -6) {
    unsigned int m = (unsigned int)(ax * 512.f + 0.5f);
    if (m > 7u) return sb | 0x08u;
    return sb | m;
  }
  unsigned int m3 = ((xb & 0x7FFFFFu) + 0x80000u) >> 20;
  unsigned int e4 = (unsigned int)(ef + 7);
  if (m3 == 8u) { m3 = 0u; e4 += 1u; }
  if (e4 >= 16u) { e4 = 15u; m3 = 6u; }
  return sb | (e4 << 3) | m3;
}
#endif

__device__ inline void fp8x4_dec(unsigned int v, float* o) {
#ifdef HW_FP8
  const f32x2 lo = __builtin_amdgcn_cvt_pk_f32_fp8((int)v, false);
  const f32x2 hi = __builtin_amdgcn_cvt_pk_f32_fp8((int)v, true);
  o[0] = lo[0]; o[1] = lo[1]; o[2] = hi[0]; o[3] = hi[1];
#else
  o[0] = fp8_dec1(v & 255u); o[1] = fp8_dec1((v >> 8) & 255u);
  o[2] = fp8_dec1((v >> 16) & 255u); o[3] = fp8_dec1(v >> 24);
#endif
}
__device__ inline unsigned short fp8x2_enc(float a, float b) {
#ifdef HW_FP8
  const int p = __builtin_amdgcn_cvt_pk_fp8_f32(a, b, 0, false);
  return (unsigned short)(p & 0xFFFF);
#else
  return (unsigned short)(fp8_enc1(a) | (fp8_enc1(b) << 8));
#endif
}

// edge pack: col(17b) << 15 | bf16(w) low 15 bits (w > 0 so sign bit = 0)
__device__ inline unsigned int epk_col(unsigned int p) { return p >> 15; }
__device__ inline float epk_w(unsigned int p) {
  return __uint_as_float((p & 0x7FFFu) << 16);
}

// ---------------------------------------------------------------------------
// Pack W1/W2 into MFMA B-fragment order (bf16); block 48 zeroes bcnt.
// ---------------------------------------------------------------------------
__device__ inline void pack_one(const float* __restrict__ W,
                                unsigned short* __restrict__ Bf,
                                int idx, int N) {
  const int lane = idx & 63;
  const int f = idx >> 6;
  const int ntile = f % (N >> 4);
  const int kstep = f / (N >> 4);
  const int k0 = (kstep << 5) + ((lane >> 4) << 3);
  const int n = (ntile << 4) + (lane & 15);
  ushort4 lo, hi;
  lo.x = f2bf(W[(size_t)(k0 + 0) * N + n]);
  lo.y = f2bf(W[(size_t)(k0 + 1) * N + n]);
  lo.z = f2bf(W[(size_t)(k0 + 2) * N + n]);
  lo.w = f2bf(W[(size_t)(k0 + 3) * N + n]);
  hi.x = f2bf(W[(size_t)(k0 + 4) * N + n]);
  hi.y = f2bf(W[(size_t)(k0 + 5) * N + n]);
  hi.z = f2bf(W[(size_t)(k0 + 6) * N + n]);
  hi.w = f2bf(W[(size_t)(k0 + 7) * N + n]);
  *(ushort4*)&Bf[(size_t)idx * 8] = lo;
  *(ushort4*)&Bf[(size_t)idx * 8 + 4] = hi;
}

__global__ __launch_bounds__(256) void pack_w_both(
    const float* __restrict__ W1, const float* __restrict__ W2,
    unsigned short* __restrict__ W1f, unsigned short* __restrict__ W2f,
    int* __restrict__ bcnt)
{
  if (blockIdx.x < 32) {
    pack_one(W1, W1f, blockIdx.x * 256 + threadIdx.x, 256);
  } else if (blockIdx.x < 48) {
    pack_one(W2, W2f, (blockIdx.x - 32) * 256 + threadIdx.x, 128);
  } else {
    if (threadIdx.x < NBUCK) bcnt[threadIdx.x] = 0;
  }
}

// ---------------------------------------------------------------------------
// partition: coarse bucket sort, LDS-staged contiguous writes, SoA output.
// ---------------------------------------------------------------------------
__global__ __launch_bounds__(512) void partition_edges(
    const int* __restrict__ row, const int* __restrict__ col,
    const float* __restrict__ w, int* __restrict__ bcnt,
    unsigned int* __restrict__ Px, unsigned int* __restrict__ Pw)
{
  __shared__ int2 stage[K3_EPB];
  __shared__ unsigned char sb[K3_EPB];
  __shared__ int hist[NBUCK], cur[NBUCK], delta[NBUCK];
  __shared__ int buf[256];
  const int t = threadIdx.x;
  const int e0 = blockIdx.x * K3_EPB;
  const int e1 = min(e0 + K3_EPB, E_EDGES);
  if (t < NBUCK) hist[t] = 0;
  __syncthreads();
  for (int i = e0 + t; i < e1; i += 512)
    atomicAdd(&hist[row[i] >> BSHIFT], 1);
  __syncthreads();
  int v = 0;
  if (t < 256) {
    v = (t < NBUCK) ? hist[t] : 0;
    buf[t] = v;
  }
  __syncthreads();
  for (int d = 1; d < 256; d <<= 1) {
    int x = 0;
    if (t < 256 && t >= d) x = buf[t - d];
    __syncthreads();
    if (t < 256) buf[t] += x;
    __syncthreads();
  }
  if (t < NBUCK) {
    const int excl = buf[t] - hist[t];
    cur[t] = excl;
    const int g = atomicAdd(&bcnt[t], hist[t]);
    delta[t] = (t * BCAP + g) - excl;
  }
  __syncthreads();
  for (int i = e0 + t; i < e1; i += 512) {
    const int r = row[i];
    const int b = r >> BSHIFT;
    const int pos = atomicAdd(&cur[b], 1);
    stage[pos] = make_int2(col[i] | ((r & 511) << 20), __float_as_int(w[i]));
    sb[pos] = (unsigned char)b;
  }
  __syncthreads();
  const int n = e1 - e0;
  for (int i = t; i < n; i += 512) {
    const int d = delta[sb[i]] + i;
    Px[d] = (unsigned int)stage[i].x;
    Pw[d] = (unsigned int)stage[i].y;
  }
}

// ---------------------------------------------------------------------------
// FUSED: blocks [0,784) = gemm1 (exact R8 structure: 256 thr / 4 waves,
// XCD-paired swizzle, 33.8KB LDS); blocks [784,980) = bucket CSR sort at
// 256 threads (memory/LDS-atomic — fills around the MFMA-heavy gemm blocks).
// Both depend only on prior launches; no cross-range ordering needed.
// ---------------------------------------------------------------------------
__global__ __launch_bounds__(256) void gemm1_csr_fused(
    const float* __restrict__ A_, const unsigned short* __restrict__ Bf,
    unsigned char* __restrict__ C,
    const int* __restrict__ bcnt, const unsigned int* __restrict__ Px,
    const unsigned int* __restrict__ Pw, int* __restrict__ offs,
    unsigned int* __restrict__ epk)
{
  __shared__ __align__(16) char smem[4 * 16 * 132 * 4];  // 33792 B
  const int t = threadIdx.x;

  if (blockIdx.x >= GEMM1_BLOCKS) {
    // ---------------- bucket CSR (256 threads) ----------------
    int* buf   = (int*)smem;            // 256
    int* rhist = buf + 256;             // 512
    int* rcur  = rhist + 512;           // 512
    int* wsum  = rcur + 512;            // 4
    const int b = blockIdx.x - GEMM1_BLOCKS;
    // block-local exclusive scan of all 196 bucket counts -> dst base
    buf[t] = (t < NBUCK) ? bcnt[t] : 0;
    __syncthreads();
    for (int d = 1; d < 256; d <<= 1) {
      int x = 0;
      if (t >= d) x = buf[t - d];
      __syncthreads();
      buf[t] += x;
      __syncthreads();
    }
    const int cnt = bcnt[b];
    const int dst0 = buf[b] - cnt;
    const int src0 = b * BCAP;
    const int row0 = b << BSHIFT;
    if (b == 0 && t == 0) offs[M_NODES] = E_EDGES;
    __syncthreads();
    rhist[t] = 0;
    rhist[t + 256] = 0;
    __syncthreads();
    for (int i = t; i < cnt; i += 256)
      atomicAdd(&rhist[(Px[src0 + i] >> 20) & 511], 1);
    __syncthreads();
    // pair-scan: thread t owns bins 2t, 2t+1
    const int lane = t & 63, wv = t >> 6;
    const int a0 = rhist[2 * t], a1 = rhist[2 * t + 1];
    const int s = a0 + a1;
    int inc = s;
#pragma unroll
    for (int d = 1; d < 64; d <<= 1) {
      const int x = __shfl_up(inc, d);
      if (lane >= d) inc += x;
    }
    if (lane == 63) wsum[wv] = inc;
    __syncthreads();
    if (t < 4) {
      int sv = wsum[t];
#pragma unroll
      for (int d = 1; d < 4; d <<= 1) {
        const int x = __shfl_up(sv, d);
        if ((int)t >= d) sv += x;
      }
      wsum[t] = sv;
    }
    __syncthreads();
    const int exclp = (wv ? wsum[wv - 1] : 0) + inc - s;
    const int o0 = dst0 + exclp;
    const int o1 = o0 + a0;
    if (row0 + 2 * t < M_NODES) offs[row0 + 2 * t] = o0;
    if (row0 + 2 * t + 1 < M_NODES) offs[row0 + 2 * t + 1] = o1;
    rcur[2 * t] = o0;
    rcur[2 * t + 1] = o1;
    __syncthreads();
    for (int i = t; i < cnt; i += 256) {
      const unsigned int px = Px[src0 + i];
      const unsigned int pw = Pw[src0 + i];
      const int rl = (px >> 20) & 511;
      const int pos = atomicAdd(&rcur[rl], 1);
      const unsigned int wb = (unsigned int)f2bf(__uint_as_float(pw));
      epk[pos] = ((px & 0xFFFFFu) << 15) | wb;
    }
    return;
  }

  // ---------------- gemm1: X1 = fp8(feat @ W1), R8 structure ----------------
  float (*cbuf)[16][132] = reinterpret_cast<float (*)[16][132]>(smem);
  const int wv = t >> 6, lane = t & 63;
  const int xcd = blockIdx.x & 7;
  const int j = blockIdx.x >> 3;
  const int bm = xcd * 49 + (j >> 1);
  const int bn = j & 1;
  if (bm >= TILESM) return;
  const int m0 = (bm << 8) + (wv << 6);
  const int n0 = bn << 7;
  const int rif = lane & 15, kg = lane >> 4;

  f32x4 acc[4][8] = {};

#pragma unroll
  for (int ks = 0; ks < 8; ++ks) {
    const int k0 = (ks << 5) + (kg << 3);
    short8 bfr[8];
    const size_t fbase = ((size_t)(ks << 4) + (n0 >> 4)) * 64 + lane;
#pragma unroll
    for (int nf = 0; nf < 8; ++nf)
      bfr[nf] = *(const short8*)&Bf[(fbase + (size_t)nf * 64) * 8];

    short8 afr[4];
#pragma unroll
    for (int mi = 0; mi < 4; ++mi) {
      const int row = m0 + (mi << 4) + rif;
      if (row < M_NODES) {
        const float* ap = &A_[(size_t)row * 256 + k0];
        const float4 lo = *(const float4*)ap;
        const float4 hi = *(const float4*)(ap + 4);
        short8 tt;
        tt[0] = (short)f2bf(lo.x); tt[1] = (short)f2bf(lo.y);
        tt[2] = (short)f2bf(lo.z); tt[3] = (short)f2bf(lo.w);
        tt[4] = (short)f2bf(hi.x); tt[5] = (short)f2bf(hi.y);
        tt[6] = (short)f2bf(hi.z); tt[7] = (short)f2bf(hi.w);
        afr[mi] = tt;
      } else {
        afr[mi] = (short8)0;
      }
    }
#pragma unroll
    for (int mi = 0; mi < 4; ++mi)
#pragma unroll
      for (int nf = 0; nf < 8; ++nf)
        acc[mi][nf] = __builtin_amdgcn_mfma_f32_16x16x32_bf16(
            afr[mi], bfr[nf], acc[mi][nf], 0, 0, 0);
  }

#pragma unroll
  for (int mi = 0; mi < 4; ++mi) {
#pragma unroll
    for (int nf = 0; nf < 8; ++nf) {
#pragma unroll
      for (int r = 0; r < 4; ++r)
        cbuf[wv][(kg << 2) + r][(nf << 4) + rif] = acc[mi][nf][r];
    }
    __syncthreads();
#pragma unroll
    for (int r = 0; r < 16; ++r) {
      const int row = m0 + (mi << 4) + r;
      if (row < M_NODES) {
        const float2 v = *(const float2*)&cbuf[wv][r][lane << 1];
        *(unsigned short*)&C[(size_t)row * 256 + n0 + (lane << 1)] =
            fp8x2_enc(v.x, v.y);
      }
    }
    __syncthreads();
  }
}

// ---------------------------------------------------------------------------
// gemm2: X2[M,128](fp8) = Hb[M,256](bf16) @ W2f. 256 thr / 4 waves, 256x128.
// ---------------------------------------------------------------------------
__global__ __launch_bounds__(256) void gemm2_mfma(
    const unsigned short* __restrict__ A_, const unsigned short* __restrict__ Bf,
    unsigned char* __restrict__ C)
{
  __shared__ float cbuf[4][16][132];
  const int wv = threadIdx.x >> 6, lane = threadIdx.x & 63;
  const int m0 = (blockIdx.x << 8) + (wv << 6);
  const int rif = lane & 15, kg = lane >> 4;

  f32x4 acc[4][8] = {};

#pragma unroll
  for (int ks = 0; ks < 8; ++ks) {
    const int k0 = (ks << 5) + (kg << 3);
    short8 bfr[8];
    const size_t fbase = ((size_t)(ks << 3)) * 64 + lane;
#pragma unroll
    for (int nf = 0; nf < 8; ++nf)
      bfr[nf] = *(const short8*)&Bf[(fbase + (size_t)nf * 64) * 8];

    short8 afr[4];
#pragma unroll
    for (int mi = 0; mi < 4; ++mi) {
      const int row = m0 + (mi << 4) + rif;
      afr[mi] = (row < M_NODES)
          ? *(const short8*)&A_[(size_t)row * 256 + k0]
          : (short8)0;
    }
#pragma unroll
    for (int mi = 0; mi < 4; ++mi)
#pragma unroll
      for (int nf = 0; nf < 8; ++nf)
        acc[mi][nf] = __builtin_amdgcn_mfma_f32_16x16x32_bf16(
            afr[mi], bfr[nf], acc[mi][nf], 0, 0, 0);
  }

#pragma unroll
  for (int mi = 0; mi < 4; ++mi) {
#pragma unroll
    for (int nf = 0; nf < 8; ++nf) {
#pragma unroll
      for (int r = 0; r < 4; ++r)
        cbuf[wv][(kg << 2) + r][(nf << 4) + rif] = acc[mi][nf][r];
    }
    __syncthreads();
#pragma unroll
    for (int r = 0; r < 16; ++r) {
      const int row = m0 + (mi << 4) + r;
      if (row < M_NODES) {
        const float2 v = *(const float2*)&cbuf[wv][r][lane << 1];
        *(unsigned short*)&C[(size_t)row * 128 + (lane << 1)] =
            fp8x2_enc(v.x, v.y);
      }
    }
    __syncthreads();
  }
}

// ---------------------------------------------------------------------------
// SPMM layer 1: Hb[r,:] = bf16(relu(sum_e w * X1fp8[col,:] + b1))
// ---------------------------------------------------------------------------
__global__ __launch_bounds__(256) void spmm1_fused(
    const int* __restrict__ offs, const unsigned int* __restrict__ epk,
    const unsigned char* __restrict__ X, const float* __restrict__ b1,
    unsigned short* __restrict__ Hb)
{
  const int w = threadIdx.x >> 6, lane = threadIdx.x & 63;
  const int half = lane >> 5, l5 = lane & 31;
  const int r = (blockIdx.x << 2) + w;
  const int s = offs[r], e = offs[r + 1];
  float a[8] = {};
  int i = s;
  for (; i + 8 <= e; i += 8) {
    unsigned int pe[4];
#pragma unroll
    for (int u = 0; u < 4; ++u) pe[u] = epk[i + (u << 1) + half];
    uint2 xv[4];
#pragma unroll
    for (int u = 0; u < 4; ++u)
      xv[u] = *(const uint2*)&X[((size_t)epk_col(pe[u]) << 8) + (l5 << 3)];
#pragma unroll
    for (int u = 0; u < 4; ++u) {
      const float wv = epk_w(pe[u]);
      float f[4], g[4];
      fp8x4_dec(xv[u].x, f);
      fp8x4_dec(xv[u].y, g);
      a[0] = fmaf(wv, f[0], a[0]); a[1] = fmaf(wv, f[1], a[1]);
      a[2] = fmaf(wv, f[2], a[2]); a[3] = fmaf(wv, f[3], a[3]);
      a[4] = fmaf(wv, g[0], a[4]); a[5] = fmaf(wv, g[1], a[5]);
      a[6] = fmaf(wv, g[2], a[6]); a[7] = fmaf(wv, g[3], a[7]);
    }
  }
  for (; i < e; i += 2) {
    const int idx = i + half;
    const unsigned int pe = (idx < e) ? epk[idx] : 0u;
    const float wv = (idx < e) ? epk_w(pe) : 0.f;
    const uint2 xw = *(const uint2*)&X[((size_t)epk_col(pe) << 8) + (l5 << 3)];
    float f[4], g[4];
    fp8x4_dec(xw.x, f);
    fp8x4_dec(xw.y, g);
    a[0] = fmaf(wv, f[0], a[0]); a[1] = fmaf(wv, f[1], a[1]);
    a[2] = fmaf(wv, f[2], a[2]); a[3] = fmaf(wv, f[3], a[3]);
    a[4] = fmaf(wv, g[0], a[4]); a[5] = fmaf(wv, g[1], a[5]);
    a[6] = fmaf(wv, g[2], a[6]); a[7] = fmaf(wv, g[3], a[7]);
  }
#pragma unroll
  for (int j = 0; j < 8; ++j) a[j] += __shfl_xor(a[j], 32);
  if (half == 0) {
    const float4 bv0 = *(const float4*)&b1[l5 << 3];
    const float4 bv1 = *(const float4*)&b1[(l5 << 3) + 4];
    short8 o;
    o[0] = (short)f2bf(fmaxf(a[0] + bv0.x, 0.f));
    o[1] = (short)f2bf(fmaxf(a[1] + bv0.y, 0.f));
    o[2] = (short)f2bf(fmaxf(a[2] + bv0.z, 0.f));
    o[3] = (short)f2bf(fmaxf(a[3] + bv0.w, 0.f));
    o[4] = (short)f2bf(fmaxf(a[4] + bv1.x, 0.f));
    o[5] = (short)f2bf(fmaxf(a[5] + bv1.y, 0.f));
    o[6] = (short)f2bf(fmaxf(a[6] + bv1.z, 0.f));
    o[7] = (short)f2bf(fmaxf(a[7] + bv1.w, 0.f));
    *(short8*)&Hb[((size_t)r << 8) + (l5 << 3)] = o;
  }
}

// ---------------------------------------------------------------------------
// SPMM layer 2: out[r,:] = b2 + sum_e w * X2fp8[col,:]   (f32 out, 128 feats)
// ---------------------------------------------------------------------------
__global__ __launch_bounds__(256) void spmm2_quad(
    const int* __restrict__ offs, const unsigned int* __restrict__ epk,
    const unsigned char* __restrict__ X, const float* __restrict__ b2,
    float* __restrict__ Y)
{
  const int w = threadIdx.x >> 6, lane = threadIdx.x & 63;
  const int q = lane >> 4, l4 = lane & 15;
  const int r = (blockIdx.x << 2) + w;
  const int s = offs[r], e = offs[r + 1];
  float a[8] = {};
  int i = s;
  for (; i + 16 <= e; i += 16) {
    unsigned int pe[4];
#pragma unroll
    for (int u = 0; u < 4; ++u) pe[u] = epk[i + (u << 2) + q];
    uint2 xv[4];
#pragma unroll
    for (int u = 0; u < 4; ++u)
      xv[u] = *(const uint2*)&X[((size_t)epk_col(pe[u]) << 7) + (l4 << 3)];
#pragma unroll
    for (int u = 0; u < 4; ++u) {
      const float wv = epk_w(pe[u]);
      float f[4], g[4];
      fp8x4_dec(xv[u].x, f);
      fp8x4_dec(xv[u].y, g);
      a[0] = fmaf(wv, f[0], a[0]); a[1] = fmaf(wv, f[1], a[1]);
      a[2] = fmaf(wv, f[2], a[2]); a[3] = fmaf(wv, f[3], a[3]);
      a[4] = fmaf(wv, g[0], a[4]); a[5] = fmaf(wv, g[1], a[5]);
      a[6] = fmaf(wv, g[2], a[6]); a[7] = fmaf(wv, g[3], a[7]);
    }
  }
  for (; i < e; i += 4) {
    const int idx = i + q;
    const unsigned int pe = (idx < e) ? epk[idx] : 0u;
    const float wv = (idx < e) ? epk_w(pe) : 0.f;
    const uint2 xw = *(const uint2*)&X[((size_t)epk_col(pe) << 7) + (l4 << 3)];
    float f[4], g[4];
    fp8x4_dec(xw.x, f);
    fp8x4_dec(xw.y, g);
    a[0] = fmaf(wv, f[0], a[0]); a[1] = fmaf(wv, f[1], a[1]);
    a[2] = fmaf(wv, f[2], a[2]); a[3] = fmaf(wv, f[3], a[3]);
    a[4] = fmaf(wv, g[0], a[4]); a[5] = fmaf(wv, g[1], a[5]);
    a[6] = fmaf(wv, g[2], a[6]); a[7] = fmaf(wv, g[3], a[7]);
  }
#pragma unroll
  for (int j = 0; j < 8; ++j) {
    a[j] += __shfl_xor(a[j], 16);
    a[j] += __shfl_xor(a[j], 32);
  }
  if (q == 0) {
    const float4 bv0 = *(const float4*)&b2[l4 << 3];
    const float4 bv1 = *(const float4*)&b2[(l4 << 3) + 4];
    float* yp = &Y[((size_t)r << 7) + (l4 << 3)];
    *(float4*)yp = make_float4(a[0] + bv0.x, a[1] + bv0.y,
                               a[2] + bv0.z, a[3] + bv0.w);
    *(float4*)(yp + 4) = make_float4(a[4] + bv1.x, a[5] + bv1.y,
                                     a[6] + bv1.z, a[7] + bv1.w);
  }
}

extern "C" void kernel_launch(void* const* d_in, const int* in_sizes, int n_in,
                              void* d_out, int out_size, void* d_ws, size_t ws_size,
                              hipStream_t stream) {
  const float* feat = (const float*)d_in[0];
  const int*   row  = (const int*)d_in[1];
  const int*   col  = (const int*)d_in[2];
  const float* ew   = (const float*)d_in[3];
  const float* W1   = (const float*)d_in[4];
  const float* b1   = (const float*)d_in[5];
  const float* W2   = (const float*)d_in[6];
  const float* b2   = (const float*)d_in[7];
  float* out = (float*)d_out;

  // workspace layout (~90 MB)
  unsigned short* Hb = (unsigned short*)d_ws;       // 100k*256 bf16 (51.2 MB)
  unsigned int* Px = (unsigned int*)d_ws;           // aliases Hb, 19.3 MB
  unsigned int* Pw = Px + (size_t)NBUCK * BCAP;     // 19.3 MB (total 38.5 < 51.2)
  unsigned char* X1 = (unsigned char*)(Hb + (size_t)M_NODES * 256);  // 25.6 MB fp8
  unsigned char* X2 = X1;                           // reuse (100k*128 fp8)
  unsigned int* epk = (unsigned int*)(X1 + (size_t)M_NODES * 256);   // 12.8 MB
  int* offs  = (int*)(epk + E_EDGES);               // 100004
  int* bcnt  = offs + 100004;                       // 200
  unsigned short* W1f = (unsigned short*)(bcnt + 200);   // 128 KB
  unsigned short* W2f = W1f + 65536;                     // 64 KB

  // ---- launch 1: pack W1/W2 + zero bcnt ----
  hipLaunchKernelGGL(pack_w_both, dim3(49), dim3(256), 0, stream,
                     W1, W2, W1f, W2f, bcnt);
  // ---- launch 2: coarse partition (SoA out) ----
  hipLaunchKernelGGL(partition_edges, dim3(K3_BLOCKS), dim3(512), 0, stream,
                     row, col, ew, bcnt, Px, Pw);
  // ---- launch 3: gemm1 (784 blocks, R8 structure) || bucket CSR (196) ----
  hipLaunchKernelGGL(gemm1_csr_fused, dim3(GEMM1_BLOCKS + NBUCK), dim3(256), 0,
                     stream, feat, W1f, X1, bcnt, Px, Pw, offs, epk);
  // ---- layer 1 aggregate: Hb = bf16(relu(A @ X1 + b1)) ----
  hipLaunchKernelGGL(spmm1_fused, dim3(M_NODES / 4), dim3(256), 0, stream,
                     offs, epk, X1, b1, Hb);
  // ---- layer 2: X2 = fp8(Hb @ W2) ----
  hipLaunchKernelGGL(gemm2_mfma, dim3(TILESM), dim3(256), 0, stream,
                     (const unsigned short*)Hb, W2f, X2);
  // ---- out = A @ X2 + b2 ----
  hipLaunchKernelGGL(spmm2_quad, dim3(M_NODES / 4), dim3(256), 0, stream,
                     offs, epk, X2, b2, out);
}

// Round 12
// 332.223 us; speedup vs baseline: 1.1183x; 1.1183x over previous
//
#include <hip/hip_runtime.h>
#include <hip/hip_bf16.h>

#define M_NODES 100000
#define E_EDGES 3200000
#define NBUCK 196          // ceil(100000 / 512)
#define BSHIFT 9           // bucket = row >> 9 (512 rows per bucket)
#define BCAP 24576         // fixed bucket capacity (avg 16327, sd ~127)
#define K3_EPB 8192        // edges per partition block
#define K3_BLOCKS 391      // ceil(E_EDGES / K3_EPB)
#define TILESM 391         // ceil(100000 / 256)

typedef __attribute__((ext_vector_type(8))) short short8;
typedef __attribute__((ext_vector_type(4))) float f32x4;
typedef __attribute__((ext_vector_type(2))) float f32x2;

__device__ inline unsigned short f2bf(float f) {
  __hip_bfloat16 h = __float2bfloat16(f);
  return __builtin_bit_cast(unsigned short, h);
}

// ---------------- fp8 e4m3 helpers (HW path on gfx950) ----------------
#if __has_builtin(__builtin_amdgcn_cvt_pk_f32_fp8) && __has_builtin(__builtin_amdgcn_cvt_pk_fp8_f32)
#define HW_FP8 1
#endif

#ifndef HW_FP8
__device__ inline float fp8_dec1(unsigned int b) {
  const unsigned int s = (b >> 7) & 1u, e = (b >> 3) & 15u, m = b & 7u;
  float v;
  if (e == 0) v = (float)m * 0.001953125f;  // 2^-9
  else v = __uint_as_float(((e + 120u) << 23) | (m << 20));
  return s ? -v : v;
}
__device__ inline unsigned int fp8_enc1(float x) {
  const unsigned int sb = (__float_as_uint(x) >> 31) << 7;
  float ax = fminf(fabsf(x), 448.f);
  if (ax < 0.0009765625f) return sb;
  const unsigned int xb = __float_as_uint(ax);
  const int ef = (int)(xb >> 23) - 127;
  if (ef < -6) {
    unsigned int m = (unsigned int)(ax * 512.f + 0.5f);
    if (m > 7u) return sb | 0x08u;
    return sb | m;
  }
  unsigned int m3 = ((xb & 0x7FFFFFu) + 0x80000u) >> 20;
  unsigned int e4 = (unsigned int)(ef + 7);
  if (m3 == 8u) { m3 = 0u; e4 += 1u; }
  if (e4 >= 16u) { e4 = 15u; m3 = 6u; }
  return sb | (e4 << 3) | m3;
}
#endif

__device__ inline void fp8x4_dec(unsigned int v, float* o) {
#ifdef HW_FP8
  const f32x2 lo = __builtin_amdgcn_cvt_pk_f32_fp8((int)v, false);
  const f32x2 hi = __builtin_amdgcn_cvt_pk_f32_fp8((int)v, true);
  o[0] = lo[0]; o[1] = lo[1]; o[2] = hi[0]; o[3] = hi[1];
#else
  o[0] = fp8_dec1(v & 255u); o[1] = fp8_dec1((v >> 8) & 255u);
  o[2] = fp8_dec1((v >> 16) & 255u); o[3] = fp8_dec1(v >> 24);
#endif
}
__device__ inline unsigned short fp8x2_enc(float a, float b) {
#ifdef HW_FP8
  const int p = __builtin_amdgcn_cvt_pk_fp8_f32(a, b, 0, false);
  return (unsigned short)(p & 0xFFFF);
#else
  return (unsigned short)(fp8_enc1(a) | (fp8_enc1(b) << 8));
#endif
}

// edge pack: col(17b) << 15 | bf16(w) low 15 bits (w > 0 so sign bit = 0)
__device__ inline unsigned int epk_col(unsigned int p) { return p >> 15; }
__device__ inline float epk_w(unsigned int p) {
  return __uint_as_float((p & 0x7FFFu) << 16);
}

// ---------------------------------------------------------------------------
// Pack W1/W2 into MFMA B-fragment order (bf16); block 48 zeroes bcnt.
// ---------------------------------------------------------------------------
__device__ inline void pack_one(const float* __restrict__ W,
                                unsigned short* __restrict__ Bf,
                                int idx, int N) {
  const int lane = idx & 63;
  const int f = idx >> 6;
  const int ntile = f % (N >> 4);
  const int kstep = f / (N >> 4);
  const int k0 = (kstep << 5) + ((lane >> 4) << 3);
  const int n = (ntile << 4) + (lane & 15);
  ushort4 lo, hi;
  lo.x = f2bf(W[(size_t)(k0 + 0) * N + n]);
  lo.y = f2bf(W[(size_t)(k0 + 1) * N + n]);
  lo.z = f2bf(W[(size_t)(k0 + 2) * N + n]);
  lo.w = f2bf(W[(size_t)(k0 + 3) * N + n]);
  hi.x = f2bf(W[(size_t)(k0 + 4) * N + n]);
  hi.y = f2bf(W[(size_t)(k0 + 5) * N + n]);
  hi.z = f2bf(W[(size_t)(k0 + 6) * N + n]);
  hi.w = f2bf(W[(size_t)(k0 + 7) * N + n]);
  *(ushort4*)&Bf[(size_t)idx * 8] = lo;
  *(ushort4*)&Bf[(size_t)idx * 8 + 4] = hi;
}

__global__ __launch_bounds__(256) void pack_w_both(
    const float* __restrict__ W1, const float* __restrict__ W2,
    unsigned short* __restrict__ W1f, unsigned short* __restrict__ W2f,
    int* __restrict__ bcnt)
{
  if (blockIdx.x < 32) {
    pack_one(W1, W1f, blockIdx.x * 256 + threadIdx.x, 256);
  } else if (blockIdx.x < 48) {
    pack_one(W2, W2f, (blockIdx.x - 32) * 256 + threadIdx.x, 128);
  } else {
    if (threadIdx.x < NBUCK) bcnt[threadIdx.x] = 0;
  }
}

// ---------------------------------------------------------------------------
// MFMA GEMM: C[M,N](fp8) = A[M,K] @ W(pre-packed bf16 frags)
// SWZ=true (gemm1, N=256, nTilesN=2): XCD-pairing swizzle so both column
// halves of one 256-row block run on the SAME XCD back-to-back -> A rows hit
// that XCD's L2 on the second read instead of going back to L3/HBM.
// ---------------------------------------------------------------------------
template<bool A_BF16, bool SWZ>
__global__ __launch_bounds__(256) void gemm_mfma(
    const void* __restrict__ A_, const unsigned short* __restrict__ Bf,
    unsigned char* __restrict__ C, int M, int K, int N, int nTilesN)
{
  __shared__ float cbuf[4][16][132];
  const int wv = threadIdx.x >> 6, lane = threadIdx.x & 63;
  int bm, bn;
  if (SWZ) {
    const int xcd = blockIdx.x & 7;
    const int j = blockIdx.x >> 3;
    bm = xcd * 49 + (j >> 1);       // 8 XCDs x 49 row-blocks
    bn = j & 1;
    if (bm >= TILESM) return;
  } else {
    bm = blockIdx.x / nTilesN;
    bn = blockIdx.x % nTilesN;
  }
  const int m0 = (bm << 8) + (wv << 6);
  const int n0 = bn << 7;
  const int rif = lane & 15, kg = lane >> 4;
  const int nf16 = N >> 4;

  f32x4 acc[4][8] = {};

  const int nK = K >> 5;
  for (int ks = 0; ks < nK; ++ks) {
    const int k0 = (ks << 5) + (kg << 3);
    short8 bfr[8];
    const size_t fbase = ((size_t)ks * nf16 + (n0 >> 4)) * 64 + lane;
#pragma unroll
    for (int nf = 0; nf < 8; ++nf)
      bfr[nf] = *(const short8*)&Bf[(fbase + (size_t)nf * 64) * 8];

    short8 afr[4];
#pragma unroll
    for (int mi = 0; mi < 4; ++mi) {
      const int row = m0 + (mi << 4) + rif;
      if (row < M) {
        if (A_BF16) {
          afr[mi] = *(const short8*)&((const unsigned short*)A_)[(size_t)row * K + k0];
        } else {
          const float* ap = &((const float*)A_)[(size_t)row * K + k0];
          const float4 lo = *(const float4*)ap;
          const float4 hi = *(const float4*)(ap + 4);
          short8 t;
          t[0] = (short)f2bf(lo.x); t[1] = (short)f2bf(lo.y);
          t[2] = (short)f2bf(lo.z); t[3] = (short)f2bf(lo.w);
          t[4] = (short)f2bf(hi.x); t[5] = (short)f2bf(hi.y);
          t[6] = (short)f2bf(hi.z); t[7] = (short)f2bf(hi.w);
          afr[mi] = t;
        }
      } else {
        afr[mi] = (short8)0;
      }
    }
#pragma unroll
    for (int mi = 0; mi < 4; ++mi)
#pragma unroll
      for (int nf = 0; nf < 8; ++nf)
        acc[mi][nf] = __builtin_amdgcn_mfma_f32_16x16x32_bf16(
            afr[mi], bfr[nf], acc[mi][nf], 0, 0, 0);
  }

#pragma unroll
  for (int mi = 0; mi < 4; ++mi) {
#pragma unroll
    for (int nf = 0; nf < 8; ++nf) {
#pragma unroll
      for (int r = 0; r < 4; ++r)
        cbuf[wv][(kg << 2) + r][(nf << 4) + rif] = acc[mi][nf][r];
    }
    __syncthreads();
#pragma unroll
    for (int r = 0; r < 16; ++r) {
      const int row = m0 + (mi << 4) + r;
      if (row < M) {
        const float2 v = *(const float2*)&cbuf[wv][r][lane << 1];
        *(unsigned short*)&C[(size_t)row * N + n0 + (lane << 1)] =
            fp8x2_enc(v.x, v.y);
      }
    }
    __syncthreads();
  }
}

// ---------------------------------------------------------------------------
// CSR build. partition_edges self-reserves fixed-capacity bucket segments
// (P base = b*BCAP) via atomicAdd on bcnt.
// ---------------------------------------------------------------------------
__global__ __launch_bounds__(512) void partition_edges(
    const int* __restrict__ row, const int* __restrict__ col,
    const float* __restrict__ w, int* __restrict__ bcnt,
    int2* __restrict__ P)
{
  __shared__ int2 stage[K3_EPB];
  __shared__ unsigned char sb[K3_EPB];
  __shared__ int hist[NBUCK], cur[NBUCK], delta[NBUCK];
  __shared__ int buf[256];
  const int t = threadIdx.x;
  const int e0 = blockIdx.x * K3_EPB;
  const int e1 = min(e0 + K3_EPB, E_EDGES);
  if (t < NBUCK) hist[t] = 0;
  __syncthreads();
  for (int i = e0 + t; i < e1; i += 512)
    atomicAdd(&hist[row[i] >> BSHIFT], 1);
  __syncthreads();
  int v = 0;
  if (t < 256) {
    v = (t < NBUCK) ? hist[t] : 0;
    buf[t] = v;
  }
  __syncthreads();
  for (int d = 1; d < 256; d <<= 1) {
    int x = 0;
    if (t < 256 && t >= d) x = buf[t - d];
    __syncthreads();
    if (t < 256) buf[t] += x;
    __syncthreads();
  }
  if (t < NBUCK) {
    const int excl = buf[t] - hist[t];
    cur[t] = excl;
    const int g = atomicAdd(&bcnt[t], hist[t]);
    delta[t] = (t * BCAP + g) - excl;
  }
  __syncthreads();
  for (int i = e0 + t; i < e1; i += 512) {
    const int r = row[i];
    const int b = r >> BSHIFT;
    const int pos = atomicAdd(&cur[b], 1);
    stage[pos] = make_int2(col[i] | ((r & 511) << 20), __float_as_int(w[i]));
    sb[pos] = (unsigned char)b;
  }
  __syncthreads();
  const int n = e1 - e0;
  for (int i = t; i < n; i += 512)
    P[delta[sb[i]] + i] = stage[i];
}

// one block per bucket: integrated 196-scan + in-L2 counting sort to CSR.
// Emits row offsets and packed 4B (col | bf16 w) edges.
__global__ __launch_bounds__(512) void bucket_csr(
    const int* __restrict__ bcnt, const int2* __restrict__ P,
    int* __restrict__ offs, unsigned int* __restrict__ epk)
{
  __shared__ int buf[256];
  __shared__ int rhist[512], rcur[512];
  __shared__ int wsum[8];
  const int t = threadIdx.x;
  const int b = blockIdx.x;
  // block-local exclusive scan of all 196 bucket counts -> dst base
  if (t < 256) buf[t] = (t < NBUCK) ? bcnt[t] : 0;
  __syncthreads();
  for (int d = 1; d < 256; d <<= 1) {
    int x = 0;
    if (t < 256 && t >= d) x = buf[t - d];
    __syncthreads();
    if (t < 256) buf[t] += x;
    __syncthreads();
  }
  const int cnt = bcnt[b];
  const int dst0 = buf[b] - cnt;
  const int src0 = b * BCAP;
  const int row0 = b << BSHIFT;
  if (b == 0 && t == 0) offs[M_NODES] = E_EDGES;
  __syncthreads();
  rhist[t] = 0;
  __syncthreads();
  for (int i = t; i < cnt; i += 512)
    atomicAdd(&rhist[(P[src0 + i].x >> 20) & 511], 1);
  __syncthreads();
  const int lane = t & 63, wv = t >> 6;
  const int v = rhist[t];
  int inc = v;
#pragma unroll
  for (int d = 1; d < 64; d <<= 1) {
    const int x = __shfl_up(inc, d);
    if (lane >= d) inc += x;
  }
  if (lane == 63) wsum[wv] = inc;
  __syncthreads();
  if (t < 8) {
    int sv = wsum[t];
#pragma unroll
    for (int d = 1; d < 8; d <<= 1) {
      const int x = __shfl_up(sv, d);
      if ((int)t >= d) sv += x;
    }
    wsum[t] = sv;
  }
  __syncthreads();
  const int excl = (wv ? wsum[wv - 1] : 0) + inc - v;
  const int gofs = dst0 + excl;
  if (row0 + t < M_NODES) offs[row0 + t] = gofs;
  rcur[t] = gofs;
  __syncthreads();
  for (int i = t; i < cnt; i += 512) {
    const int2 p = P[src0 + i];
    const int rl = (p.x >> 20) & 511;
    const int pos = atomicAdd(&rcur[rl], 1);
    const unsigned int wb = (unsigned int)f2bf(__int_as_float(p.y));
    epk[pos] = (((unsigned int)p.x & 0xFFFFFu) << 15) | wb;
  }
}

// ---------------------------------------------------------------------------
// SPMM layer 1: Hb[r,:] = bf16(relu(sum_e w * X1fp8[col,:] + b1))
// One wave per row; 2 edges per step (half-wave x 8B = 256B row); 8 in flight.
// ---------------------------------------------------------------------------
__global__ __launch_bounds__(256) void spmm1_fused(
    const int* __restrict__ offs, const unsigned int* __restrict__ epk,
    const unsigned char* __restrict__ X, const float* __restrict__ b1,
    unsigned short* __restrict__ Hb)
{
  const int w = threadIdx.x >> 6, lane = threadIdx.x & 63;
  const int half = lane >> 5, l5 = lane & 31;
  const int r = (blockIdx.x << 2) + w;
  const int s = offs[r], e = offs[r + 1];
  float a[8] = {};
  int i = s;
  for (; i + 8 <= e; i += 8) {
    unsigned int pe[4];
#pragma unroll
    for (int u = 0; u < 4; ++u) pe[u] = epk[i + (u << 1) + half];
    uint2 xv[4];
#pragma unroll
    for (int u = 0; u < 4; ++u)
      xv[u] = *(const uint2*)&X[((size_t)epk_col(pe[u]) << 8) + (l5 << 3)];
#pragma unroll
    for (int u = 0; u < 4; ++u) {
      const float wv = epk_w(pe[u]);
      float f[4], g[4];
      fp8x4_dec(xv[u].x, f);
      fp8x4_dec(xv[u].y, g);
      a[0] = fmaf(wv, f[0], a[0]); a[1] = fmaf(wv, f[1], a[1]);
      a[2] = fmaf(wv, f[2], a[2]); a[3] = fmaf(wv, f[3], a[3]);
      a[4] = fmaf(wv, g[0], a[4]); a[5] = fmaf(wv, g[1], a[5]);
      a[6] = fmaf(wv, g[2], a[6]); a[7] = fmaf(wv, g[3], a[7]);
    }
  }
  for (; i < e; i += 2) {
    const int idx = i + half;
    const unsigned int pe = (idx < e) ? epk[idx] : 0u;
    const float wv = (idx < e) ? epk_w(pe) : 0.f;
    const uint2 xw = *(const uint2*)&X[((size_t)epk_col(pe) << 8) + (l5 << 3)];
    float f[4], g[4];
    fp8x4_dec(xw.x, f);
    fp8x4_dec(xw.y, g);
    a[0] = fmaf(wv, f[0], a[0]); a[1] = fmaf(wv, f[1], a[1]);
    a[2] = fmaf(wv, f[2], a[2]); a[3] = fmaf(wv, f[3], a[3]);
    a[4] = fmaf(wv, g[0], a[4]); a[5] = fmaf(wv, g[1], a[5]);
    a[6] = fmaf(wv, g[2], a[6]); a[7] = fmaf(wv, g[3], a[7]);
  }
#pragma unroll
  for (int j = 0; j < 8; ++j) a[j] += __shfl_xor(a[j], 32);
  if (half == 0) {
    const float4 bv0 = *(const float4*)&b1[l5 << 3];
    const float4 bv1 = *(const float4*)&b1[(l5 << 3) + 4];
    short8 o;
    o[0] = (short)f2bf(fmaxf(a[0] + bv0.x, 0.f));
    o[1] = (short)f2bf(fmaxf(a[1] + bv0.y, 0.f));
    o[2] = (short)f2bf(fmaxf(a[2] + bv0.z, 0.f));
    o[3] = (short)f2bf(fmaxf(a[3] + bv0.w, 0.f));
    o[4] = (short)f2bf(fmaxf(a[4] + bv1.x, 0.f));
    o[5] = (short)f2bf(fmaxf(a[5] + bv1.y, 0.f));
    o[6] = (short)f2bf(fmaxf(a[6] + bv1.z, 0.f));
    o[7] = (short)f2bf(fmaxf(a[7] + bv1.w, 0.f));
    *(short8*)&Hb[((size_t)r << 8) + (l5 << 3)] = o;
  }
}

// ---------------------------------------------------------------------------
// SPMM layer 2: out[r,:] = b2 + sum_e w * X2fp8[col,:]   (f32 out, 128 feats)
// One wave per row; 4 edges per step (16 lanes x 8B = 128B row); 16 in flight.
// ---------------------------------------------------------------------------
__global__ __launch_bounds__(256) void spmm2_quad(
    const int* __restrict__ offs, const unsigned int* __restrict__ epk,
    const unsigned char* __restrict__ X, const float* __restrict__ b2,
    float* __restrict__ Y)
{
  const int w = threadIdx.x >> 6, lane = threadIdx.x & 63;
  const int q = lane >> 4, l4 = lane & 15;
  const int r = (blockIdx.x << 2) + w;
  const int s = offs[r], e = offs[r + 1];
  float a[8] = {};
  int i = s;
  for (; i + 16 <= e; i += 16) {
    unsigned int pe[4];
#pragma unroll
    for (int u = 0; u < 4; ++u) pe[u] = epk[i + (u << 2) + q];
    uint2 xv[4];
#pragma unroll
    for (int u = 0; u < 4; ++u)
      xv[u] = *(const uint2*)&X[((size_t)epk_col(pe[u]) << 7) + (l4 << 3)];
#pragma unroll
    for (int u = 0; u < 4; ++u) {
      const float wv = epk_w(pe[u]);
      float f[4], g[4];
      fp8x4_dec(xv[u].x, f);
      fp8x4_dec(xv[u].y, g);
      a[0] = fmaf(wv, f[0], a[0]); a[1] = fmaf(wv, f[1], a[1]);
      a[2] = fmaf(wv, f[2], a[2]); a[3] = fmaf(wv, f[3], a[3]);
      a[4] = fmaf(wv, g[0], a[4]); a[5] = fmaf(wv, g[1], a[5]);
      a[6] = fmaf(wv, g[2], a[6]); a[7] = fmaf(wv, g[3], a[7]);
    }
  }
  for (; i < e; i += 4) {
    const int idx = i + q;
    const unsigned int pe = (idx < e) ? epk[idx] : 0u;
    const float wv = (idx < e) ? epk_w(pe) : 0.f;
    const uint2 xw = *(const uint2*)&X[((size_t)epk_col(pe) << 7) + (l4 << 3)];
    float f[4], g[4];
    fp8x4_dec(xw.x, f);
    fp8x4_dec(xw.y, g);
    a[0] = fmaf(wv, f[0], a[0]); a[1] = fmaf(wv, f[1], a[1]);
    a[2] = fmaf(wv, f[2], a[2]); a[3] = fmaf(wv, f[3], a[3]);
    a[4] = fmaf(wv, g[0], a[4]); a[5] = fmaf(wv, g[1], a[5]);
    a[6] = fmaf(wv, g[2], a[6]); a[7] = fmaf(wv, g[3], a[7]);
  }
#pragma unroll
  for (int j = 0; j < 8; ++j) {
    a[j] += __shfl_xor(a[j], 16);
    a[j] += __shfl_xor(a[j], 32);
  }
  if (q == 0) {
    const float4 bv0 = *(const float4*)&b2[l4 << 3];
    const float4 bv1 = *(const float4*)&b2[(l4 << 3) + 4];
    float* yp = &Y[((size_t)r << 7) + (l4 << 3)];
    *(float4*)yp = make_float4(a[0] + bv0.x, a[1] + bv0.y,
                               a[2] + bv0.z, a[3] + bv0.w);
    *(float4*)(yp + 4) = make_float4(a[4] + bv1.x, a[5] + bv1.y,
                                     a[6] + bv1.z, a[7] + bv1.w);
  }
}

extern "C" void kernel_launch(void* const* d_in, const int* in_sizes, int n_in,
                              void* d_out, int out_size, void* d_ws, size_t ws_size,
                              hipStream_t stream) {
  const float* feat = (const float*)d_in[0];
  const int*   row  = (const int*)d_in[1];
  const int*   col  = (const int*)d_in[2];
  const float* ew   = (const float*)d_in[3];
  const float* W1   = (const float*)d_in[4];
  const float* b1   = (const float*)d_in[5];
  const float* W2   = (const float*)d_in[6];
  const float* b2   = (const float*)d_in[7];
  float* out = (float*)d_out;

  // workspace layout (~90 MB)
  unsigned short* Hb = (unsigned short*)d_ws;       // 100k*256 bf16 (51.2 MB)
  int2* P = (int2*)d_ws;                            // aliases Hb (dead early), 38.5 MB
  unsigned char* X1 = (unsigned char*)(Hb + (size_t)M_NODES * 256);  // 25.6 MB fp8
  unsigned char* X2 = X1;                           // reuse (100k*128 fp8)
  unsigned int* epk = (unsigned int*)(X1 + (size_t)M_NODES * 256);   // 12.8 MB
  int* offs  = (int*)(epk + E_EDGES);               // 100004
  int* bcnt  = offs + 100004;                       // 200
  unsigned short* W1f = (unsigned short*)(bcnt + 200);   // 128 KB
  unsigned short* W2f = W1f + 65536;                     // 64 KB

  // ---- weight pack + bcnt zero (one launch) ----
  hipLaunchKernelGGL(pack_w_both, dim3(49), dim3(256), 0, stream,
                     W1, W2, W1f, W2f, bcnt);
  // ---- CSR build ----
  hipLaunchKernelGGL(partition_edges, dim3(K3_BLOCKS), dim3(512), 0, stream,
                     row, col, ew, bcnt, P);
  hipLaunchKernelGGL(bucket_csr, dim3(NBUCK), dim3(512), 0, stream,
                     bcnt, P, offs, epk);

  // ---- layer 1 ----
  // X1 = fp8(feat @ W1)   (XCD-paired swizzle, 8*49*2 = 784 blocks)
  hipLaunchKernelGGL((gemm_mfma<false, true>), dim3(784), dim3(256), 0,
                     stream, (const void*)feat, W1f, X1, M_NODES, 256, 256, 2);
  // Hb = bf16(relu(A @ X1 + b1))
  hipLaunchKernelGGL(spmm1_fused, dim3(M_NODES / 4), dim3(256), 0, stream,
                     offs, epk, X1, b1, Hb);

  // ---- layer 2 ----
  // X2 = fp8(Hb @ W2)
  hipLaunchKernelGGL((gemm_mfma<true, false>), dim3(TILESM), dim3(256), 0,
                     stream, (const void*)Hb, W2f, X2, M_NODES, 256, 128, 1);
  // out = A @ X2 + b2
  hipLaunchKernelGGL(spmm2_quad, dim3(M_NODES / 4), dim3(256), 0, stream,
                     offs, epk, X2, b2, out);
}